// Round 3
// baseline (102.393 us; speedup 1.0000x reference)
//
#include <hip/hip_runtime.h>
#include <stdint.h>

#define BATCH   2048
#define INDIM   512
#define OUTDIM  512
#define SDIM    8
#define KTOT    4096      // 8 slices * 512
#define SPLITK  8         // one s-slice per block

typedef __attribute__((ext_vector_type(4))) float  f32x4;
typedef __attribute__((ext_vector_type(8))) __bf16 bf16x8;
typedef __attribute__((ext_vector_type(8))) unsigned short u16x8;

__device__ __forceinline__ unsigned short f2bf(float x) {
  unsigned int u = __float_as_uint(x);
  u += 0x7fffu + ((u >> 16) & 1u);      // round-to-nearest-even
  return (unsigned short)(u >> 16);
}

__device__ __forceinline__ void llds16(const void* g, void* s) {
  __builtin_amdgcn_global_load_lds(
      (__attribute__((address_space(1))) void*)g,
      (__attribute__((address_space(3))) void*)s, 16, 0, 0);
}

__device__ __forceinline__ void mkbasis(float t, float* bs) {
  bs[0] = 1.0f; bs[1] = t; bs[2] = t * t; bs[3] = bs[2] * t;
  const float kn[4] = {0.2f, 0.4f, 0.6f, 0.8f};
#pragma unroll
  for (int c = 0; c < 4; ++c) {
    float d = fmaxf(t - kn[c], 0.0f);
    bs[4 + c] = d * d * d;
  }
}

// ---------------------------------------------------------------------------
// prep (round-1 version, proven):
//   blocks [   0, 512): Bt[n][k] = bf16(W[k*512+n])  (transpose-convert)
//   blocks [ 512,1024): Fbf[b][i] = bf16(inp[b][1+i]); basis table (f32)
//   blocks [1024,2048): out[b][o] = sum_s basis[b][s]*b_wts[s][o] (bias init,
//                       replaces memset; gemm atomically adds on top)
// ---------------------------------------------------------------------------
__global__ __launch_bounds__(256) void prep_kernel(
    const float* __restrict__ inp, const float* __restrict__ W,
    const float* __restrict__ bwts, unsigned short* __restrict__ Fbf,
    unsigned short* __restrict__ Btf, float* __restrict__ Bas,
    float* __restrict__ out) {
  const int tid = threadIdx.x;
  const int bx  = blockIdx.x;
  if (bx < 512) {
    const int kt = bx >> 3, ntile = bx & 7;
    const int k0 = kt * 64, n0 = ntile * 64;
    __shared__ float Ts[64][65];           // [n_local][k_local], padded
#pragma unroll
    for (int p = 0; p < 4; ++p) {
      const int r  = (tid >> 4) + p * 16;  // k-local
      const int c4 = (tid & 15) * 4;       // n-local
      float4 v = *(const float4*)&W[(size_t)(k0 + r) * 512 + n0 + c4];
      Ts[c4 + 0][r] = v.x; Ts[c4 + 1][r] = v.y;
      Ts[c4 + 2][r] = v.z; Ts[c4 + 3][r] = v.w;
    }
    __syncthreads();
    const int nl  = tid >> 2;              // 0..63
    const int kcc = (tid & 3) * 16;        // 0,16,32,48
    u16x8 o0, o1;
#pragma unroll
    for (int q = 0; q < 8; ++q) {
      o0[q] = f2bf(Ts[nl][kcc + q]);
      o1[q] = f2bf(Ts[nl][kcc + 8 + q]);
    }
    unsigned short* dst = Btf + (size_t)(n0 + nl) * KTOT + k0 + kcc;
    *(u16x8*)dst = o0;
    *(u16x8*)(dst + 8) = o1;
  } else if (bx < 1024) {
    const int b0   = (bx - 512) * 4;
    const int b    = b0 + (tid >> 6);
    const int i0   = (tid & 63) * 8;
    const float* row = inp + (size_t)b * (INDIM + 1);
    u16x8 o;
#pragma unroll
    for (int q = 0; q < 8; ++q) o[q] = f2bf(row[1 + i0 + q]);
    *(u16x8*)(Fbf + (size_t)b * INDIM + i0) = o;
    if (tid < 4) {
      const int bb = b0 + tid;
      float t = inp[(size_t)bb * (INDIM + 1)];
      float bs[8]; mkbasis(t, bs);
      f32x4 lo = {bs[0], bs[1], bs[2], bs[3]};
      f32x4 hi = {bs[4], bs[5], bs[6], bs[7]};
      *(f32x4*)(Bas + (size_t)bb * 8)     = lo;
      *(f32x4*)(Bas + (size_t)bb * 8 + 4) = hi;
    }
  } else {
    const int bb = (bx - 1024) * 2 + (tid >> 7);
    const int o0 = (tid & 127) * 4;
    float t = inp[(size_t)bb * (INDIM + 1)];
    float bs[8]; mkbasis(t, bs);
    float4 a = make_float4(0.f, 0.f, 0.f, 0.f);
#pragma unroll
    for (int s = 0; s < 8; ++s) {
      float4 wv = *(const float4*)&bwts[s * OUTDIM + o0];
      a.x += bs[s] * wv.x; a.y += bs[s] * wv.y;
      a.z += bs[s] * wv.z; a.w += bs[s] * wv.w;
    }
    *(float4*)&out[(size_t)bb * OUTDIM + o0] = a;
  }
}

// ---------------------------------------------------------------------------
// GEMM: out += basis[:,s] * (F @ Wk[s]) for s = blockIdx kc.
// m97-structure: 128x128 tile, BK=64, 4 waves each computing a 64x64 quadrant
// as 4x4 16x16x32 fragments -> 32 MFMA : 16 ds_read_b128 per wave-K-step.
// SPLITK=8 -> 512 blocks (2/CU, 2 waves/SIMD), K=512 = 8 K-steps per block,
// exactly ONE s-slice per block (uniform basis scale in epilogue).
// llds16 staging, XOR swizzle chunk^(row&7) on the GLOBAL source (m104 rule).
// ---------------------------------------------------------------------------
__global__ __launch_bounds__(256, 2) void gemm_kernel(
    const unsigned short* __restrict__ Fbf,
    const unsigned short* __restrict__ Btf,
    const float* __restrict__ Bas,
    float* __restrict__ out) {
  const int tid  = threadIdx.x;
  const int s    = blockIdx.x & (SPLITK - 1);     // s-slice 0..7
  const int tile = blockIdx.x >> 3;               // 0..63
  const int nt = tile & 3, mt = tile >> 2;        // 4 n-tiles x 16 m-tiles
  const int m0 = mt * 128, n0 = nt * 128;
  const int l = tid & 63, w = tid >> 6;
  const int wm = w >> 1, wn = w & 1;              // wave -> 64x64 quadrant
  const int quad = l >> 4, lr = l & 15;

  __shared__ __align__(16) unsigned short As[128 * 64];   // 16 KB
  __shared__ __align__(16) unsigned short Bs[128 * 64];   // 16 KB

  f32x4 acc[4][4] = {};

  // staging map: thread -> row sr (of 32), chunk pc; 4 calls cover 128 rows.
  // LDS dst for call j = As + j*4096B's worth... = elem j*2048 + tid*8
  // (wave-uniform base + lane*16B). Global source chunk lc = pc ^ (sr&7)
  // (j*32 doesn't change row&7).
  const int sr = tid >> 3, pc = tid & 7;
  const int lc = pc ^ (sr & 7);
  const unsigned short* Ag = Fbf + (size_t)(m0 + sr) * INDIM + lc * 8;
  const unsigned short* Bg = Btf + (size_t)(n0 + sr) * KTOT + (size_t)s * 512 + lc * 8;

  // fragment read offsets: logical chunk q of row r lives at q ^ (r&7);
  // row&7 == lr&7 for every 16-aligned row base.
  const int sx = lr & 7;
  const int c0 = (quad ^ sx) * 8;          // ks = 0: k in [quad*8, quad*8+8)
  const int c1 = ((4 + quad) ^ sx) * 8;    // ks = 1: k in [32+quad*8, ...)
  int arow[4], brow[4];
#pragma unroll
  for (int i = 0; i < 4; ++i) {
    arow[i] = (wm * 64 + i * 16 + lr) * 64;
    brow[i] = (wn * 64 + i * 16 + lr) * 64;
  }

  for (int it = 0; it < 8; ++it) {
    const int koff = it * 64;
#pragma unroll
    for (int j = 0; j < 4; ++j) {
      llds16(Ag + koff + (size_t)(j * 32) * INDIM, &As[j * 2048 + tid * 8]);
      llds16(Bg + koff + (size_t)(j * 32) * KTOT,  &Bs[j * 2048 + tid * 8]);
    }
    __syncthreads();

    bf16x8 a0[4], a1[4], b0[4], b1[4];
#pragma unroll
    for (int i = 0; i < 4; ++i) {
      a0[i] = *(const bf16x8*)&As[arow[i] + c0];
      a1[i] = *(const bf16x8*)&As[arow[i] + c1];
      b0[i] = *(const bf16x8*)&Bs[brow[i] + c0];
      b1[i] = *(const bf16x8*)&Bs[brow[i] + c1];
    }
#pragma unroll
    for (int i = 0; i < 4; ++i)
#pragma unroll
      for (int j = 0; j < 4; ++j) {
        acc[i][j] = __builtin_amdgcn_mfma_f32_16x16x32_bf16(a0[i], b0[j], acc[i][j], 0, 0, 0);
        acc[i][j] = __builtin_amdgcn_mfma_f32_16x16x32_bf16(a1[i], b1[j], acc[i][j], 0, 0, 0);
      }
    __syncthreads();
  }

  // epilogue: scale by basis[row][s] (f32, exact) and atomically add.
  // C/D layout (verified m89/m91): col = lane&15, row = quad*4 + reg.
  float bsv[4][4];
#pragma unroll
  for (int i = 0; i < 4; ++i) {
    const int rowb = m0 + wm * 64 + i * 16 + quad * 4;
#pragma unroll
    for (int r = 0; r < 4; ++r)
      bsv[i][r] = Bas[(size_t)(rowb + r) * 8 + s];
  }
#pragma unroll
  for (int i = 0; i < 4; ++i) {
    const int rowb = m0 + wm * 64 + i * 16 + quad * 4;
#pragma unroll
    for (int j = 0; j < 4; ++j) {
      const int col = n0 + wn * 64 + j * 16 + lr;
      float* o = out + (size_t)rowb * OUTDIM + col;
#pragma unroll
      for (int r = 0; r < 4; ++r)
        unsafeAtomicAdd(o + (size_t)r * OUTDIM, acc[i][j][r] * bsv[i][r]);
    }
  }
}

extern "C" void kernel_launch(void* const* d_in, const int* in_sizes, int n_in,
                              void* d_out, int out_size, void* d_ws, size_t ws_size,
                              hipStream_t stream) {
  const float* inp  = (const float*)d_in[0];   // (2048, 513)
  const float* W    = (const float*)d_in[1];   // (8, 262144) == (4096, 512) row-major
  const float* bwts = (const float*)d_in[2];   // (8, 512)
  float* out = (float*)d_out;

  unsigned short* Fbf = (unsigned short*)d_ws;                  // 2 MB
  unsigned short* Btf = Fbf + (size_t)BATCH * INDIM;            // 4 MB
  float*          Bas = (float*)(Btf + (size_t)OUTDIM * KTOT);  // 64 KB

  prep_kernel<<<2048, 256, 0, stream>>>(inp, W, bwts, Fbf, Btf, Bas, out);
  gemm_kernel<<<(BATCH / 128) * (OUTDIM / 128) * SPLITK, 256, 0, stream>>>(Fbf, Btf, Bas, out);
}

// Round 4
// 87.317 us; speedup vs baseline: 1.1727x; 1.1727x over previous
//
#include <hip/hip_runtime.h>
#include <stdint.h>

#define BATCH   2048
#define INDIM   512
#define OUTDIM  512
#define SDIM    8
#define KTOT    4096
#define PSTRIDE 68                 // f32 per plane row (bank-skewed: 68%32=4)
#define PSZ     (64 * PSTRIDE)     // 4352 f32 per plane

typedef __attribute__((ext_vector_type(4))) float  f32x4;
typedef __attribute__((ext_vector_type(8))) __bf16 bf16x8;
typedef __attribute__((ext_vector_type(8))) unsigned short u16x8;

__device__ __forceinline__ unsigned short f2bf(float x) {
  unsigned int u = __float_as_uint(x);
  u += 0x7fffu + ((u >> 16) & 1u);      // round-to-nearest-even
  return (unsigned short)(u >> 16);
}

__device__ __forceinline__ void llds16(const void* g, void* s) {
  __builtin_amdgcn_global_load_lds(
      (__attribute__((address_space(1))) void*)g,
      (__attribute__((address_space(3))) void*)s, 16, 0, 0);
}

__device__ __forceinline__ void mkbasis(float t, float* bs) {
  bs[0] = 1.0f; bs[1] = t; bs[2] = t * t; bs[3] = bs[2] * t;
  const float kn[4] = {0.2f, 0.4f, 0.6f, 0.8f};
#pragma unroll
  for (int c = 0; c < 4; ++c) {
    float d = fmaxf(t - kn[c], 0.0f);
    bs[4 + c] = d * d * d;
  }
}

// ---------------------------------------------------------------------------
// prep (proven transpose/convert paths only; bias handled inside gemm now):
//   blocks [  0, 512): Bt[n][k] = bf16(W[k*512+n])
//   blocks [512,1024): Fbf[b][i] = bf16(inp[b][1+i]); basis table (f32)
// ---------------------------------------------------------------------------
__global__ __launch_bounds__(256) void prep_kernel(
    const float* __restrict__ inp, const float* __restrict__ W,
    unsigned short* __restrict__ Fbf, unsigned short* __restrict__ Btf,
    float* __restrict__ Bas) {
  const int tid = threadIdx.x;
  const int bx  = blockIdx.x;
  if (bx < 512) {
    const int kt = bx >> 3, ntile = bx & 7;
    const int k0 = kt * 64, n0 = ntile * 64;
    __shared__ float Ts[64][65];           // [n_local][k_local], padded
#pragma unroll
    for (int p = 0; p < 4; ++p) {
      const int r  = (tid >> 4) + p * 16;  // k-local
      const int c4 = (tid & 15) * 4;       // n-local
      float4 v = *(const float4*)&W[(size_t)(k0 + r) * 512 + n0 + c4];
      Ts[c4 + 0][r] = v.x; Ts[c4 + 1][r] = v.y;
      Ts[c4 + 2][r] = v.z; Ts[c4 + 3][r] = v.w;
    }
    __syncthreads();
    const int nl  = tid >> 2;              // 0..63
    const int kcc = (tid & 3) * 16;        // 0,16,32,48
    u16x8 o0, o1;
#pragma unroll
    for (int q = 0; q < 8; ++q) {
      o0[q] = f2bf(Ts[nl][kcc + q]);
      o1[q] = f2bf(Ts[nl][kcc + 8 + q]);
    }
    unsigned short* dst = Btf + (size_t)(n0 + nl) * KTOT + k0 + kcc;
    *(u16x8*)dst = o0;
    *(u16x8*)(dst + 8) = o1;
  } else {
    const int b0   = (bx - 512) * 4;
    const int b    = b0 + (tid >> 6);
    const int i0   = (tid & 63) * 8;
    const float* row = inp + (size_t)b * (INDIM + 1);
    u16x8 o;
#pragma unroll
    for (int q = 0; q < 8; ++q) o[q] = f2bf(row[1 + i0 + q]);
    *(u16x8*)(Fbf + (size_t)b * INDIM + i0) = o;
    if (tid < 4) {
      const int bb = b0 + tid;
      float t = inp[(size_t)bb * (INDIM + 1)];
      float bs[8]; mkbasis(t, bs);
      f32x4 lo = {bs[0], bs[1], bs[2], bs[3]};
      f32x4 hi = {bs[4], bs[5], bs[6], bs[7]};
      *(f32x4*)(Bas + (size_t)bb * 8)     = lo;
      *(f32x4*)(Bas + (size_t)bb * 8 + 4) = hi;
    }
  }
}

// ---------------------------------------------------------------------------
// GEMM, atomic-free: grid 256 (one 64x64 tile/block, 1/CU), 512 thr = 8 waves
// (2/SIMD). Wave w computes the FULL tile for slice s=w (K=512):
//   A (64x512 bf16, shared by all slices) staged ONCE in LDS, XOR-swizzled
//   (chunk ^ row&7) via pre-swizzled global source (m104 rule);
//   B fragments read DIRECTLY from global (L2-resident; quads of a wave cover
//   full 64B lines) -> NO barriers in the main loop, waves slip freely.
// Density per K-step/wave: 16 MFMA : 4 ds_read_b128 : 4 global_load_dwordx4.
// Epilogue: raw partials -> 8 bank-skewed LDS planes (reuse A area after a
// barrier), then each thread stores  out[r][c] = sum_w Bas[r][w]*(plane_w[r][c]
// + b_wts[w][c])  -- bias folded in, pure coalesced stores, zero atomics.
// ---------------------------------------------------------------------------
__global__ __launch_bounds__(512, 2) void gemm_kernel(
    const unsigned short* __restrict__ Fbf,
    const unsigned short* __restrict__ Btf,
    const float* __restrict__ Bas,
    const float* __restrict__ bwts,
    float* __restrict__ out) {
  const int tid  = threadIdx.x;
  const int tile = blockIdx.x;           // 256 = 32 m-tiles x 8 n-tiles
  const int nt = tile & 7, mt = tile >> 3;
  const int m0 = mt * 64, n0 = nt * 64;
  const int w = tid >> 6;                // wave id == slice id, 0..7
  const int l = tid & 63;
  const int quad = l >> 4, lr = l & 15;

  __shared__ __align__(16) float smem[8 * PSZ];       // 139264 B
  unsigned short* Alds = (unsigned short*)smem;       // A region: [0, 64 KB)

  // ---- stage A (64 x 512 bf16) once: 8 llds16 per thread ----
#pragma unroll
  for (int j = 0; j < 8; ++j) {
    const int f   = j * 512 + tid;       // flat 16B-chunk index 0..4095
    const int row = f >> 6;              // 0..63
    const int cs  = (f & 63) ^ (row & 7);
    llds16(Fbf + (size_t)(m0 + row) * INDIM + cs * 8, &Alds[f * 8]);
  }
  __syncthreads();                       // drains llds; A ready for all waves

  // ---- B base pointers: row (n0 + j*16 + lr), slice w, quad's 8-elem chunk
  const unsigned short* bptr[4];
#pragma unroll
  for (int j = 0; j < 4; ++j)
    bptr[j] = Btf + (size_t)(n0 + j * 16 + lr) * KTOT + w * 512 + quad * 8;

  const int sx = lr & 7;
  f32x4 acc[4][4] = {};

#pragma unroll 4
  for (int ks = 0; ks < 16; ++ks) {      // K = 512, 32 per step, no barriers
    bf16x8 bfr[4], afr[4];
#pragma unroll
    for (int j = 0; j < 4; ++j)
      bfr[j] = *(const bf16x8*)(bptr[j] + ks * 32);
    const int c = ((ks * 4 + quad) ^ sx) * 8;
#pragma unroll
    for (int i = 0; i < 4; ++i)
      afr[i] = *(const bf16x8*)&Alds[(i * 16 + lr) * 512 + c];
#pragma unroll
    for (int i = 0; i < 4; ++i)
#pragma unroll
      for (int j = 0; j < 4; ++j)
        acc[i][j] = __builtin_amdgcn_mfma_f32_16x16x32_bf16(afr[i], bfr[j], acc[i][j], 0, 0, 0);
  }

  __syncthreads();                       // everyone done reading Alds

  // ---- dump raw partial to plane w (C/D: row = quad*4+reg, col = lr) ----
  float* P = smem + w * PSZ;
#pragma unroll
  for (int i = 0; i < 4; ++i)
#pragma unroll
    for (int j = 0; j < 4; ++j)
#pragma unroll
      for (int r = 0; r < 4; ++r)
        P[(i * 16 + quad * 4 + r) * PSTRIDE + j * 16 + lr] = acc[i][j][r];

  __syncthreads();

  // ---- reduce + bias + store: thread -> row tid>>3, cols (tid&7)*8 .. +8 ----
  const int row  = tid >> 3;
  const int col8 = (tid & 7) * 8;
  const float* brow = Bas + (size_t)(m0 + row) * 8;
  f32x4 s0 = {}, s1 = {};
#pragma unroll
  for (int ww = 0; ww < 8; ++ww) {
    const float bw = brow[ww];
    const float* Pr = smem + ww * PSZ + row * PSTRIDE + col8;
    const float* Wr = bwts + (size_t)ww * OUTDIM + n0 + col8;
    f32x4 v0 = *(const f32x4*)Pr + *(const f32x4*)Wr;
    f32x4 v1 = *(const f32x4*)(Pr + 4) + *(const f32x4*)(Wr + 4);
    s0 += v0 * bw;
    s1 += v1 * bw;
  }
  float* op = out + (size_t)(m0 + row) * OUTDIM + n0 + col8;
  *(f32x4*)op       = s0;
  *(f32x4*)(op + 4) = s1;
}

extern "C" void kernel_launch(void* const* d_in, const int* in_sizes, int n_in,
                              void* d_out, int out_size, void* d_ws, size_t ws_size,
                              hipStream_t stream) {
  const float* inp  = (const float*)d_in[0];   // (2048, 513)
  const float* W    = (const float*)d_in[1];   // (8, 262144) == (4096, 512) row-major
  const float* bwts = (const float*)d_in[2];   // (8, 512)
  float* out = (float*)d_out;

  unsigned short* Fbf = (unsigned short*)d_ws;                  // 2 MB
  unsigned short* Btf = Fbf + (size_t)BATCH * INDIM;            // 4 MB
  float*          Bas = (float*)(Btf + (size_t)OUTDIM * KTOT);  // 64 KB

  prep_kernel<<<1024, 256, 0, stream>>>(inp, W, Fbf, Btf, Bas);
  gemm_kernel<<<(BATCH / 64) * (OUTDIM / 64), 512, 0, stream>>>(Fbf, Btf, Bas, bwts, out);
}